// Round 3
// baseline (1041.492 us; speedup 1.0000x reference)
//
#include <hip/hip_runtime.h>
#include <hip/hip_bf16.h>

// DeepSeekMoE on MI355X. FP32 inputs/output per reference; bf16 MFMA compute
// internally. Sparse top-2 dispatch (exact vs dense reference: non-topk gates
// are 0). Gate path uses split-bf16 (hi/lo) 3-term GEMM + fp64 layer-2 so the
// top-2 expert selection matches the fp32 numpy reference.

using bf16 = __hip_bfloat16;
typedef __attribute__((ext_vector_type(8))) short short8;
typedef __attribute__((ext_vector_type(4))) float float4v;

#define T_TOK 8192
#define DDIM  1024
#define HDIM  2048
#define NEXP  8

__device__ __forceinline__ float bf2f(short s) {
  unsigned u = ((unsigned)(unsigned short)s) << 16;
  return __builtin_bit_cast(float, u);
}
__device__ __forceinline__ unsigned short f2bf(float f) {
  unsigned u = __builtin_bit_cast(unsigned, f);
  unsigned r = (u + 0x7fffu + ((u >> 16) & 1u)) >> 16;   // RNE
  return (unsigned short)r;
}
__device__ __forceinline__ float gelu_erf_f(float x) {
  return 0.5f * x * (1.0f + erff(x * 0.70710678118654752f));
}
__device__ __forceinline__ float gelu_tanh_f(float x) {
  float t = tanhf(0.7978845608028654f * (x + 0.044715f * x * x * x));
  return 0.5f * x * (1.0f + t);
}

// ---------------- cast x fp32 -> bf16 hi + bf16 residual ----------------
__global__ __launch_bounds__(256) void cast_split_x(
    const float* __restrict__ x, bf16* __restrict__ xh, bf16* __restrict__ xl)
{
  long i = ((long)blockIdx.x * 256 + threadIdx.x) * 4;
  float4v v = *(const float4v*)(x + i);
  short4 h, l;
  short* hp = (short*)&h; short* lp = (short*)&l;
  #pragma unroll
  for (int j = 0; j < 4; ++j) {
    unsigned short hb = f2bf(v[j]);
    hp[j] = (short)hb;
    lp[j] = (short)f2bf(v[j] - bf2f((short)hb));
  }
  *(short4*)((short*)xh + i) = h;
  *(short4*)((short*)xl + i) = l;
}

// ------------- transpose+cast fp32 [R,C] -> bf16 [C,R], batched z -------------
template<bool SPLIT>
__global__ __launch_bounds__(256) void transpose_cast(
    const float* __restrict__ in, bf16* __restrict__ out,
    bf16* __restrict__ outl, int R, int C)
{
  __shared__ float tile[32][33];
  long b = blockIdx.z;
  const float* ip = in + b * (long)R * C;
  short* op = (short*)out + b * (long)R * C;
  short* opl = SPLIT ? (short*)outl + b * (long)R * C : nullptr;
  int c0 = blockIdx.x * 32, r0 = blockIdx.y * 32;
  int tx = threadIdx.x & 31, ty = threadIdx.x >> 5;
  #pragma unroll
  for (int i = ty; i < 32; i += 8)
    tile[i][tx] = ip[(long)(r0 + i) * C + c0 + tx];
  __syncthreads();
  #pragma unroll
  for (int i = ty; i < 32; i += 8) {
    float v = tile[tx][i];
    unsigned short hb = f2bf(v);
    op[(long)(c0 + i) * R + r0 + tx] = (short)hb;
    if (SPLIT)
      opl[(long)(c0 + i) * R + r0 + tx] = (short)f2bf(v - bf2f((short)hb));
  }
}

// ---------------- tiled MFMA GEMM: C = act(A @ B^T + bias) ----------------
// A [M,Kd] bf16 (ldA), Bt [N,Kd] bf16 (+z*strideB), bias fp32 [N] (+z*strideBias).
// GATHER: 0 dense; 1 A-row = perm[i]>>1 (token); 2 A-row = perm[i] (slot).
// Gathered: C row = perm[i], M_eff = counts[z], early-exit tiles.
// ACT: 0 none, 1 gelu(erf), 2 gelu(tanh). WEIGHTED: scale by wslot[slot].
// SPLIT: accumulate A@Bt + A@Btl + Al@Bt (split-bf16 high precision; dense only).
template<int ACT, typename OutT, int GATHER, bool WEIGHTED, bool SPLIT>
__global__ __launch_bounds__(256) void gemm_bt(
    const bf16* __restrict__ A, const bf16* __restrict__ Bt,
    const bf16* __restrict__ Al, const bf16* __restrict__ Btl,
    const float* __restrict__ bias, OutT* __restrict__ Cmat,
    int M, int N, int Kd, int ldA,
    long strideB, long strideBias,
    const int* __restrict__ perm, const int* __restrict__ counts,
    const float* __restrict__ wslot)
{
  __shared__ __align__(16) bf16 lA[128 * 32];
  __shared__ __align__(16) bf16 lB[128 * 32];
  __shared__ int permT[128];

  const int tid = threadIdx.x;
  const int tile_n = blockIdx.x, tile_m = blockIdx.y, z = blockIdx.z;

  int Meff = M;
  if (GATHER) {
    const int* perm_z = perm + (long)z * T_TOK;
    Meff = counts[z];
    if (tile_m * 128 >= Meff) return;   // uniform early-exit (before barriers)
    if (tid < 128) {
      int i = tile_m * 128 + tid;
      permT[tid] = perm_z[i < Meff ? i : (Meff - 1)];
    }
    __syncthreads();
  }
  const float* biasz = bias + (long)z * strideBias;

  // --- staging thread mapping: 16B chunk per thread per half-tile ---
  const int i0 = tid >> 2;          // row-in-tile for chunk c0 (0..63)
  const int kc = (tid & 3) * 8;     // k element offset within 32-wide slab
  long rowA0, rowA1;
  if (GATHER) {
    int p0 = permT[i0], p1 = permT[i0 + 64];
    rowA0 = (GATHER == 1) ? (p0 >> 1) : p0;
    rowA1 = (GATHER == 1) ? (p1 >> 1) : p1;
  } else {
    rowA0 = (long)tile_m * 128 + i0;
    rowA1 = rowA0 + 64;
  }
  short8* sA0 = (short8*)&lA[tid * 8];
  short8* sA1 = (short8*)&lA[(tid + 256) * 8];
  short8* sB0 = (short8*)&lB[tid * 8];
  short8* sB1 = (short8*)&lB[(tid + 256) * 8];

  const int lane = tid & 63;
  const int wave = tid >> 6;
  const int wm = (wave & 1) * 64;
  const int wn = (wave >> 1) * 64;
  const int fr = lane & 15;         // m/n index within 16x16 tile
  const int fk = (lane >> 4) * 8;   // k offset for A/B fragments

  float4v acc[4][4];
  #pragma unroll
  for (int i = 0; i < 4; ++i)
    #pragma unroll
    for (int j = 0; j < 4; ++j) acc[i][j] = {0.f, 0.f, 0.f, 0.f};

  #pragma unroll 1
  for (int ps = 0; ps < (SPLIT ? 3 : 1); ++ps) {
    const bf16* Ap = (SPLIT && ps == 2) ? Al : A;
    const bf16* Bp = (SPLIT && ps == 1) ? Btl : Bt;
    const bf16* aBase0 = Ap + rowA0 * ldA + kc;
    const bf16* aBase1 = Ap + rowA1 * ldA + kc;
    const bf16* bBase0 = Bp + (long)z * strideB
                       + ((long)tile_n * 128 + i0) * Kd + kc;
    const bf16* bBase1 = bBase0 + (long)64 * Kd;

    for (int k0 = 0; k0 < Kd; k0 += 32) {
      short8 ra0 = *(const short8*)(aBase0 + k0);
      short8 ra1 = *(const short8*)(aBase1 + k0);
      short8 rb0 = *(const short8*)(bBase0 + k0);
      short8 rb1 = *(const short8*)(bBase1 + k0);
      __syncthreads();                 // prev iter's LDS readers done
      *sA0 = ra0; *sA1 = ra1; *sB0 = rb0; *sB1 = rb1;   // ds_write_b128
      __syncthreads();                 // LDS visible

      short8 af[4], bfr[4];
      #pragma unroll
      for (int mi = 0; mi < 4; ++mi)
        af[mi] = *(const short8*)&lA[(wm + mi * 16 + fr) * 32 + fk];
      #pragma unroll
      for (int ni = 0; ni < 4; ++ni)
        bfr[ni] = *(const short8*)&lB[(wn + ni * 16 + fr) * 32 + fk];
      #pragma unroll
      for (int mi = 0; mi < 4; ++mi)
        #pragma unroll
        for (int ni = 0; ni < 4; ++ni)
          acc[mi][ni] = __builtin_amdgcn_mfma_f32_16x16x32_bf16(
              af[mi], bfr[ni], acc[mi][ni], 0, 0, 0);
    }
  }

  // --- epilogue: C/D layout col(n)=lane&15, row(m)=(lane>>4)*4+reg ---
  const int rq = (lane >> 4) * 4;
  #pragma unroll
  for (int mi = 0; mi < 4; ++mi) {
    #pragma unroll
    for (int r = 0; r < 4; ++r) {
      int irow = wm + mi * 16 + rq + r;
      int gi = tile_m * 128 + irow;
      long crow;
      bool valid = true;
      float w = 1.f;
      if (GATHER) {
        valid = gi < Meff;
        int p = permT[irow];
        crow = p;
        if (WEIGHTED) w = valid ? wslot[p] : 0.f;
      } else {
        crow = gi;
      }
      if (valid) {
        #pragma unroll
        for (int ni = 0; ni < 4; ++ni) {
          int gcol = tile_n * 128 + wn + ni * 16 + fr;
          float v = acc[mi][ni][r] + biasz[gcol];
          if (ACT == 1) v = gelu_erf_f(v);
          else if (ACT == 2) v = gelu_tanh_f(v);
          if (WEIGHTED) v *= w;
          long cidx = crow * (long)N + gcol;
          if (sizeof(OutT) == 4) ((float*)Cmat)[cidx] = v;
          else ((unsigned short*)Cmat)[cidx] = f2bf(v);
        }
      }
    }
  }
}

// -------- gating: logits = G1 @ gw2 + gb2 (double acc), softmax, top-2 --------
__global__ __launch_bounds__(256) void gating_kernel(
    const float* __restrict__ G1, const float* __restrict__ gw2,
    const float* __restrict__ gb2, int* __restrict__ counts,
    int* __restrict__ perm, float* __restrict__ wslot)
{
  int t = blockIdx.x;
  int tid = threadIdx.x;
  double p[NEXP];
  #pragma unroll
  for (int e = 0; e < NEXP; ++e) p[e] = 0.0;

  const float* grow = G1 + (long)t * HDIM;
  for (int j = 0; j < HDIM / 256; ++j) {
    int h = j * 256 + tid;
    float g = grow[h];
    float4v w0 = *(const float4v*)&gw2[h * NEXP];
    float4v w1 = *(const float4v*)&gw2[h * NEXP + 4];
    #pragma unroll
    for (int e = 0; e < 4; ++e) {
      p[e]     += (double)g * (double)w0[e];
      p[e + 4] += (double)g * (double)w1[e];
    }
  }
  #pragma unroll
  for (int off = 32; off >= 1; off >>= 1)
    #pragma unroll
    for (int e = 0; e < NEXP; ++e) p[e] += __shfl_xor(p[e], off);

  __shared__ double red[4][NEXP];
  int wv = tid >> 6, lane = tid & 63;
  if (lane == 0)
    #pragma unroll
    for (int e = 0; e < NEXP; ++e) red[wv][e] = p[e];
  __syncthreads();

  if (tid == 0) {
    double lg[NEXP];
    #pragma unroll
    for (int e = 0; e < NEXP; ++e)
      lg[e] = red[0][e] + red[1][e] + red[2][e] + red[3][e] + (double)gb2[e];
    int i1 = 0;
    for (int e = 1; e < NEXP; ++e) if (lg[e] > lg[i1]) i1 = e;     // ties -> lowest idx
    int i2 = (i1 == 0) ? 1 : 0;
    for (int e = 0; e < NEXP; ++e) {
      if (e == i1) continue;
      if (lg[e] > lg[i2]) i2 = e;
    }
    double m = lg[i1], s = 0.0;
    #pragma unroll
    for (int e = 0; e < NEXP; ++e) s += exp(lg[e] - m);
    float w1 = (float)(exp(lg[i1] - m) / s);
    float w2 = (float)(exp(lg[i2] - m) / s);
    int pos = atomicAdd(&counts[i1], 1);
    perm[i1 * T_TOK + pos] = t * 2;
    wslot[t * 2] = w1;
    pos = atomicAdd(&counts[i2], 1);
    perm[i2 * T_TOK + pos] = t * 2 + 1;
    wslot[t * 2 + 1] = w2;
  }
}

// ---------------- combine: out(fp32) += Rout[2t] + Rout[2t+1] ----------------
__global__ __launch_bounds__(256) void combine_kernel(
    const bf16* __restrict__ Rout, float* __restrict__ out)
{
  long idx = (long)blockIdx.x * 256 + threadIdx.x;  // one 8-elem chunk each
  long t = idx >> 7;                                // D/8 = 128 chunks per token
  long dc = idx & 127;
  const short* rs = (const short*)Rout;
  short8 a = *(const short8*)&rs[(2 * t) * DDIM + dc * 8];
  short8 b = *(const short8*)&rs[(2 * t + 1) * DDIM + dc * 8];
  float* op = out + idx * 8;
  float4v o0 = *(const float4v*)op;
  float4v o1 = *(const float4v*)(op + 4);
  #pragma unroll
  for (int j = 0; j < 4; ++j) o0[j] += bf2f(a[j]) + bf2f(b[j]);
  #pragma unroll
  for (int j = 0; j < 4; ++j) o1[j] += bf2f(a[j + 4]) + bf2f(b[j + 4]);
  *(float4v*)op = o0;
  *(float4v*)(op + 4) = o1;
}

extern "C" void kernel_launch(void* const* d_in, const int* in_sizes, int n_in,
                              void* d_out, int out_size, void* d_ws, size_t ws_size,
                              hipStream_t stream)
{
  const float* x   = (const float*)d_in[0];
  // d_in[1] = task_ids (unused by reference)
  const float* gw1 = (const float*)d_in[2];
  const float* gb1 = (const float*)d_in[3];
  const float* gw2 = (const float*)d_in[4];
  const float* gb2 = (const float*)d_in[5];
  const float* We1 = (const float*)d_in[6];
  const float* be1 = (const float*)d_in[7];
  const float* We2 = (const float*)d_in[8];
  const float* be2 = (const float*)d_in[9];
  const float* Ws1 = (const float*)d_in[10];
  const float* bs1 = (const float*)d_in[11];
  const float* Ws2 = (const float*)d_in[12];
  const float* bs2 = (const float*)d_in[13];
  float* out = (float*)d_out;

  // ---- workspace layout (176.3 MiB, lifetime-overlapped) ----
  char* ws = (char*)d_ws;
  bf16*  xb     = (bf16*)(ws + 0);              // 16 MiB [T,D] hi
  bf16*  We1t   = (bf16*)(ws + 16777216);       // 32 MiB [E,H,D]
  bf16*  Rout   = (bf16*)(ws + 16777216);       // 32 MiB [2T,D] (reuses We1t)
  bf16*  We2t   = (bf16*)(ws + 50331648);       // 32 MiB [E,D,H]
  bf16*  Ws1t   = (bf16*)(ws + 83886080);       //  4 MiB [H,D]
  bf16*  Ws2t   = (bf16*)(ws + 88080384);       //  4 MiB [D,H]
  int*   counts = (int*)(ws + 92274688);        // 1 KiB pad
  float* wslot  = (float*)(ws + 92275712);      // 64 KiB [2T]
  int*   perm   = (int*)(ws + 92341248);        // 256 KiB [E,T]
  bf16*  xl     = (bf16*)(ws + 92603392);       // 16 MiB [T,D] lo
  bf16*  gw1h   = (bf16*)(ws + 109380608);      //  4 MiB [H,D] hi
  bf16*  gw1l   = (bf16*)(ws + 113574912);      //  4 MiB [H,D] lo
  float* G1     = (float*)(ws + 117769216);     // 64 MiB [T,H] fp32
  bf16*  S1     = (bf16*)(ws + 117769216);      // 32 MiB [T,H]  (reuses G1)
  bf16*  Hrt    = (bf16*)(ws + 117769216);      // 64 MiB [2T,H] (reuses G1/S1)

  hipMemsetAsync(counts, 0, NEXP * sizeof(int), stream);

  dim3 blk(256);
  // x cast (hi+lo)
  cast_split_x<<<dim3((T_TOK * DDIM) / 1024), blk, 0, stream>>>(x, xb, xl);
  // weight cast+transpose ([K,N] fp32 -> [N,K] bf16)
  transpose_cast<true ><<<dim3(HDIM/32, DDIM/32, 1), blk, 0, stream>>>(gw1, gw1h, gw1l, DDIM, HDIM);
  transpose_cast<false><<<dim3(HDIM/32, DDIM/32, 1), blk, 0, stream>>>(Ws1, Ws1t, nullptr, DDIM, HDIM);
  transpose_cast<false><<<dim3(DDIM/32, HDIM/32, 1), blk, 0, stream>>>(Ws2, Ws2t, nullptr, HDIM, DDIM);
  transpose_cast<false><<<dim3(HDIM/32, DDIM/32, NEXP), blk, 0, stream>>>(We1, We1t, nullptr, DDIM, HDIM);
  transpose_cast<false><<<dim3(DDIM/32, HDIM/32, NEXP), blk, 0, stream>>>(We2, We2t, nullptr, HDIM, DDIM);

  // gate GEMM1 (split-bf16, fp32 out): G1 = gelu_erf(x @ gw1 + gb1)
  gemm_bt<1, float, 0, false, true><<<dim3(HDIM/128, T_TOK/128, 1), blk, 0, stream>>>(
      xb, gw1h, xl, gw1l, gb1, G1, T_TOK, HDIM, DDIM, DDIM, 0, 0,
      nullptr, nullptr, nullptr);
  // gating: fp64 layer-2 + softmax + top-2 dispatch lists
  gating_kernel<<<dim3(T_TOK), blk, 0, stream>>>(G1, gw2, gb2, counts, perm, wslot);
  // shared expert
  gemm_bt<2, bf16, 0, false, false><<<dim3(HDIM/128, T_TOK/128, 1), blk, 0, stream>>>(
      xb, Ws1t, nullptr, nullptr, bs1, S1, T_TOK, HDIM, DDIM, DDIM, 0, 0,
      nullptr, nullptr, nullptr);
  gemm_bt<0, float, 0, false, false><<<dim3(DDIM/128, T_TOK/128, 1), blk, 0, stream>>>(
      S1, Ws2t, nullptr, nullptr, bs2, out, T_TOK, DDIM, HDIM, HDIM, 0, 0,
      nullptr, nullptr, nullptr);
  // routed experts (gathered)
  gemm_bt<2, bf16, 1, false, false><<<dim3(HDIM/128, T_TOK/128, NEXP), blk, 0, stream>>>(
      xb, We1t, nullptr, nullptr, be1, Hrt, T_TOK, HDIM, DDIM, DDIM,
      (long)HDIM * DDIM, HDIM, perm, counts, nullptr);
  gemm_bt<0, bf16, 2, true, false><<<dim3(DDIM/128, T_TOK/128, NEXP), blk, 0, stream>>>(
      Hrt, We2t, nullptr, nullptr, be2, Rout, T_TOK, DDIM, HDIM, HDIM,
      (long)DDIM * HDIM, DDIM, perm, counts, wslot);
  // final combine (fp32)
  combine_kernel<<<dim3((T_TOK * DDIM) / 2048), blk, 0, stream>>>(Rout, out);
}

// Round 4
// 901.617 us; speedup vs baseline: 1.1551x; 1.1551x over previous
//
#include <hip/hip_runtime.h>
#include <hip/hip_bf16.h>

// DeepSeekMoE on MI355X. FP32 inputs/output per reference; bf16 MFMA compute.
// Sparse top-2 dispatch (exact vs dense reference: non-topk gates are 0).
// Gate layer-1 uses split-bf16 3-term GEMM (fp32-level precision) so top-2
// selection matches the fp32 numpy reference; layer-2 logits in fp32.
// R4: (1) gating rebuilt as logits(wave/token) + ballot-aggregated dispatch
//     (R3's gating_kernel was 196us: 8-address atomic storm + fp64 tail);
// (2) global_load_lds width=16 staging restored (m97 structure; R1's NaN was
//     the fp32-as-bf16 dtype bug, not the staging).

using bf16 = __hip_bfloat16;
typedef __attribute__((ext_vector_type(8))) short short8;
typedef __attribute__((ext_vector_type(4))) float float4v;

#define T_TOK 8192
#define DDIM  1024
#define HDIM  2048
#define NEXP  8

__device__ __forceinline__ float bf2f(short s) {
  unsigned u = ((unsigned)(unsigned short)s) << 16;
  return __builtin_bit_cast(float, u);
}
__device__ __forceinline__ unsigned short f2bf(float f) {
  unsigned u = __builtin_bit_cast(unsigned, f);
  unsigned r = (u + 0x7fffu + ((u >> 16) & 1u)) >> 16;   // RNE
  return (unsigned short)r;
}
__device__ __forceinline__ float gelu_erf_f(float x) {
  return 0.5f * x * (1.0f + erff(x * 0.70710678118654752f));
}
__device__ __forceinline__ float gelu_tanh_f(float x) {
  float t = tanhf(0.7978845608028654f * (x + 0.044715f * x * x * x));
  return 0.5f * x * (1.0f + t);
}
__device__ __forceinline__ void gld_lds16(const bf16* g, bf16* l) {
  __builtin_amdgcn_global_load_lds(
      (const __attribute__((address_space(1))) void*)g,
      (__attribute__((address_space(3))) void*)l, 16, 0, 0);
}

// ---------------- cast x fp32 -> bf16 hi + bf16 residual ----------------
__global__ __launch_bounds__(256) void cast_split_x(
    const float* __restrict__ x, bf16* __restrict__ xh, bf16* __restrict__ xl)
{
  long i = ((long)blockIdx.x * 256 + threadIdx.x) * 4;
  float4v v = *(const float4v*)(x + i);
  short4 h, l;
  short* hp = (short*)&h; short* lp = (short*)&l;
  #pragma unroll
  for (int j = 0; j < 4; ++j) {
    unsigned short hb = f2bf(v[j]);
    hp[j] = (short)hb;
    lp[j] = (short)f2bf(v[j] - bf2f((short)hb));
  }
  *(short4*)((short*)xh + i) = h;
  *(short4*)((short*)xl + i) = l;
}

// ------------- transpose+cast fp32 [R,C] -> bf16 [C,R], batched z -------------
template<bool SPLIT>
__global__ __launch_bounds__(256) void transpose_cast(
    const float* __restrict__ in, bf16* __restrict__ out,
    bf16* __restrict__ outl, int R, int C)
{
  __shared__ float tile[32][33];
  long b = blockIdx.z;
  const float* ip = in + b * (long)R * C;
  short* op = (short*)out + b * (long)R * C;
  short* opl = SPLIT ? (short*)outl + b * (long)R * C : nullptr;
  int c0 = blockIdx.x * 32, r0 = blockIdx.y * 32;
  int tx = threadIdx.x & 31, ty = threadIdx.x >> 5;
  #pragma unroll
  for (int i = ty; i < 32; i += 8)
    tile[i][tx] = ip[(long)(r0 + i) * C + c0 + tx];
  __syncthreads();
  #pragma unroll
  for (int i = ty; i < 32; i += 8) {
    float v = tile[tx][i];
    unsigned short hb = f2bf(v);
    op[(long)(c0 + i) * R + r0 + tx] = (short)hb;
    if (SPLIT)
      opl[(long)(c0 + i) * R + r0 + tx] = (short)f2bf(v - bf2f((short)hb));
  }
}

// ---------------- tiled MFMA GEMM: C = act(A @ B^T + bias) ----------------
// A [M,Kd] bf16 (ldA), Bt [N,Kd] bf16 (+z*strideB), bias fp32 [N] (+z*strideBias).
// GATHER: 0 dense; 1 A-row = perm[i]>>1 (token); 2 A-row = perm[i] (slot).
// Gathered: C row = perm[i], M_eff = counts[z], early-exit tiles.
// ACT: 0 none, 1 gelu(erf), 2 gelu(tanh). WEIGHTED: scale by wslot[slot].
// SPLIT: accumulate A@Bt + A@Btl + Al@Bt (split-bf16 high precision; dense only).
template<int ACT, typename OutT, int GATHER, bool WEIGHTED, bool SPLIT>
__global__ __launch_bounds__(256) void gemm_bt(
    const bf16* __restrict__ A, const bf16* __restrict__ Bt,
    const bf16* __restrict__ Al, const bf16* __restrict__ Btl,
    const float* __restrict__ bias, OutT* __restrict__ Cmat,
    int M, int N, int Kd, int ldA,
    long strideB, long strideBias,
    const int* __restrict__ perm, const int* __restrict__ counts,
    const float* __restrict__ wslot)
{
  __shared__ __align__(16) bf16 lA[128 * 32];
  __shared__ __align__(16) bf16 lB[128 * 32];
  __shared__ int permT[128];

  const int tid = threadIdx.x;
  const int tile_n = blockIdx.x, tile_m = blockIdx.y, z = blockIdx.z;

  int Meff = M;
  if (GATHER) {
    const int* perm_z = perm + (long)z * T_TOK;
    Meff = counts[z];
    if (tile_m * 128 >= Meff) return;   // uniform early-exit (before barriers)
    if (tid < 128) {
      int i = tile_m * 128 + tid;
      permT[tid] = perm_z[i < Meff ? i : (Meff - 1)];
    }
    __syncthreads();
  }
  const float* biasz = bias + (long)z * strideBias;

  // --- staging: 16B chunk per thread per half-tile; LDS dest is
  //     wave-uniform base + lane*16 (global_load_lds requirement) ---
  const int i0 = tid >> 2;          // row-in-tile for chunk c0 (0..63)
  const int kc = (tid & 3) * 8;     // k element offset within 32-wide slab
  long rowA0, rowA1;
  if (GATHER) {
    int p0 = permT[i0], p1 = permT[i0 + 64];
    rowA0 = (GATHER == 1) ? (p0 >> 1) : p0;
    rowA1 = (GATHER == 1) ? (p1 >> 1) : p1;
  } else {
    rowA0 = (long)tile_m * 128 + i0;
    rowA1 = rowA0 + 64;
  }
  bf16* lA0 = &lA[tid * 8];
  bf16* lA1 = &lA[(tid + 256) * 8];
  bf16* lB0 = &lB[tid * 8];
  bf16* lB1 = &lB[(tid + 256) * 8];

  const int lane = tid & 63;
  const int wave = tid >> 6;
  const int wm = (wave & 1) * 64;
  const int wn = (wave >> 1) * 64;
  const int fr = lane & 15;         // m/n index within 16x16 tile
  const int fk = (lane >> 4) * 8;   // k offset for A/B fragments

  float4v acc[4][4];
  #pragma unroll
  for (int i = 0; i < 4; ++i)
    #pragma unroll
    for (int j = 0; j < 4; ++j) acc[i][j] = {0.f, 0.f, 0.f, 0.f};

  #pragma unroll 1
  for (int ps = 0; ps < (SPLIT ? 3 : 1); ++ps) {
    const bf16* Ap = (SPLIT && ps == 2) ? Al : A;
    const bf16* Bp = (SPLIT && ps == 1) ? Btl : Bt;
    const bf16* aBase0 = Ap + rowA0 * ldA + kc;
    const bf16* aBase1 = Ap + rowA1 * ldA + kc;
    const bf16* bBase0 = Bp + (long)z * strideB
                       + ((long)tile_n * 128 + i0) * Kd + kc;
    const bf16* bBase1 = bBase0 + (long)64 * Kd;

    for (int k0 = 0; k0 < Kd; k0 += 32) {
      gld_lds16(aBase0 + k0, lA0);
      gld_lds16(aBase1 + k0, lA1);
      gld_lds16(bBase0 + k0, lB0);
      gld_lds16(bBase1 + k0, lB1);
      __syncthreads();               // drains vmcnt -> LDS tile visible

      short8 af[4], bfr[4];
      #pragma unroll
      for (int mi = 0; mi < 4; ++mi)
        af[mi] = *(const short8*)&lA[(wm + mi * 16 + fr) * 32 + fk];
      #pragma unroll
      for (int ni = 0; ni < 4; ++ni)
        bfr[ni] = *(const short8*)&lB[(wn + ni * 16 + fr) * 32 + fk];
      #pragma unroll
      for (int mi = 0; mi < 4; ++mi)
        #pragma unroll
        for (int ni = 0; ni < 4; ++ni)
          acc[mi][ni] = __builtin_amdgcn_mfma_f32_16x16x32_bf16(
              af[mi], bfr[ni], acc[mi][ni], 0, 0, 0);
      __syncthreads();               // all readers done before next staging
    }
  }

  // --- epilogue: C/D layout col(n)=lane&15, row(m)=(lane>>4)*4+reg ---
  const int rq = (lane >> 4) * 4;
  #pragma unroll
  for (int mi = 0; mi < 4; ++mi) {
    #pragma unroll
    for (int r = 0; r < 4; ++r) {
      int irow = wm + mi * 16 + rq + r;
      int gi = tile_m * 128 + irow;
      long crow;
      bool valid = true;
      float w = 1.f;
      if (GATHER) {
        valid = gi < Meff;
        int p = permT[irow];
        crow = p;
        if (WEIGHTED) w = valid ? wslot[p] : 0.f;
      } else {
        crow = gi;
      }
      if (valid) {
        #pragma unroll
        for (int ni = 0; ni < 4; ++ni) {
          int gcol = tile_n * 128 + wn + ni * 16 + fr;
          float v = acc[mi][ni][r] + biasz[gcol];
          if (ACT == 1) v = gelu_erf_f(v);
          else if (ACT == 2) v = gelu_tanh_f(v);
          if (WEIGHTED) v *= w;
          long cidx = crow * (long)N + gcol;
          if (sizeof(OutT) == 4) ((float*)Cmat)[cidx] = v;
          else ((unsigned short*)Cmat)[cidx] = f2bf(v);
        }
      }
    }
  }
}

// -------- logits: one wave per token; fp32 reduce; top-2 + softmax --------
__global__ __launch_bounds__(256) void logits_kernel(
    const float* __restrict__ G1, const float* __restrict__ gw2,
    const float* __restrict__ gb2, int* __restrict__ tidx,
    float* __restrict__ wslot)
{
  int wv = threadIdx.x >> 6, lane = threadIdx.x & 63;
  int t = blockIdx.x * 4 + wv;
  const float* grow = G1 + (long)t * HDIM;
  float acc[NEXP];
  #pragma unroll
  for (int e = 0; e < NEXP; ++e) acc[e] = 0.f;
  for (int j = 0; j < HDIM / 64; ++j) {
    int h = j * 64 + lane;
    float g = grow[h];                      // coalesced across the wave
    float4v w0 = *(const float4v*)&gw2[h * NEXP];
    float4v w1 = *(const float4v*)&gw2[h * NEXP + 4];
    #pragma unroll
    for (int e = 0; e < 4; ++e) {
      acc[e]     += g * w0[e];
      acc[e + 4] += g * w1[e];
    }
  }
  #pragma unroll
  for (int off = 32; off >= 1; off >>= 1)
    #pragma unroll
    for (int e = 0; e < NEXP; ++e) acc[e] += __shfl_xor(acc[e], off);

  if (lane == 0) {
    float lg[NEXP];
    #pragma unroll
    for (int e = 0; e < NEXP; ++e) lg[e] = acc[e] + gb2[e];
    int i1 = 0;
    for (int e = 1; e < NEXP; ++e) if (lg[e] > lg[i1]) i1 = e;   // ties -> lowest
    int i2 = (i1 == 0) ? 1 : 0;
    for (int e = 0; e < NEXP; ++e) {
      if (e == i1) continue;
      if (lg[e] > lg[i2]) i2 = e;
    }
    float m = lg[i1], s = 0.f;
    #pragma unroll
    for (int e = 0; e < NEXP; ++e) s += expf(lg[e] - m);
    float inv = 1.f / s;
    tidx[2 * t]     = i1;
    tidx[2 * t + 1] = i2;
    wslot[2 * t]     = expf(lg[i1] - m) * inv;
    wslot[2 * t + 1] = expf(lg[i2] - m) * inv;
  }
}

// -------- dispatch: ballot-aggregated per-expert slot lists --------
__global__ __launch_bounds__(256) void dispatch_kernel(
    const int* __restrict__ tidx, int* __restrict__ counts,
    int* __restrict__ perm)
{
  int t = blockIdx.x * 256 + threadIdx.x;
  int lane = threadIdx.x & 63;
  #pragma unroll
  for (int k = 0; k < 2; ++k) {
    int e = tidx[2 * t + k];
    #pragma unroll
    for (int ex = 0; ex < NEXP; ++ex) {
      unsigned long long m = __ballot(e == ex);
      if (m) {                                 // wave-uniform
        int leader = __ffsll((unsigned long long)m) - 1;
        int base = 0;
        if (lane == leader) base = atomicAdd(&counts[ex], __popcll(m));
        base = __shfl(base, leader);
        if (e == ex) {
          int pos = base + __popcll(m & ((1ULL << lane) - 1ULL));
          perm[ex * T_TOK + pos] = 2 * t + k;
        }
      }
    }
  }
}

// ---------------- combine: out(fp32) += Rout[2t] + Rout[2t+1] ----------------
__global__ __launch_bounds__(256) void combine_kernel(
    const bf16* __restrict__ Rout, float* __restrict__ out)
{
  long idx = (long)blockIdx.x * 256 + threadIdx.x;  // one 8-elem chunk each
  long t = idx >> 7;                                // D/8 = 128 chunks per token
  long dc = idx & 127;
  const short* rs = (const short*)Rout;
  short8 a = *(const short8*)&rs[(2 * t) * DDIM + dc * 8];
  short8 b = *(const short8*)&rs[(2 * t + 1) * DDIM + dc * 8];
  float* op = out + idx * 8;
  float4v o0 = *(const float4v*)op;
  float4v o1 = *(const float4v*)(op + 4);
  #pragma unroll
  for (int j = 0; j < 4; ++j) o0[j] += bf2f(a[j]) + bf2f(b[j]);
  #pragma unroll
  for (int j = 0; j < 4; ++j) o1[j] += bf2f(a[j + 4]) + bf2f(b[j + 4]);
  *(float4v*)op = o0;
  *(float4v*)(op + 4) = o1;
}

extern "C" void kernel_launch(void* const* d_in, const int* in_sizes, int n_in,
                              void* d_out, int out_size, void* d_ws, size_t ws_size,
                              hipStream_t stream)
{
  const float* x   = (const float*)d_in[0];
  // d_in[1] = task_ids (unused by reference)
  const float* gw1 = (const float*)d_in[2];
  const float* gb1 = (const float*)d_in[3];
  const float* gw2 = (const float*)d_in[4];
  const float* gb2 = (const float*)d_in[5];
  const float* We1 = (const float*)d_in[6];
  const float* be1 = (const float*)d_in[7];
  const float* We2 = (const float*)d_in[8];
  const float* be2 = (const float*)d_in[9];
  const float* Ws1 = (const float*)d_in[10];
  const float* bs1 = (const float*)d_in[11];
  const float* Ws2 = (const float*)d_in[12];
  const float* bs2 = (const float*)d_in[13];
  float* out = (float*)d_out;

  // ---- workspace layout (176.3 MiB, lifetime-overlapped) ----
  char* ws = (char*)d_ws;
  bf16*  xb     = (bf16*)(ws + 0);              // 16 MiB [T,D] hi
  bf16*  We1t   = (bf16*)(ws + 16777216);       // 32 MiB [E,H,D]
  bf16*  Rout   = (bf16*)(ws + 16777216);       // 32 MiB [2T,D] (reuses We1t)
  bf16*  We2t   = (bf16*)(ws + 50331648);       // 32 MiB [E,D,H]
  bf16*  Ws1t   = (bf16*)(ws + 83886080);       //  4 MiB [H,D]
  bf16*  Ws2t   = (bf16*)(ws + 88080384);       //  4 MiB [D,H]
  int*   counts = (int*)(ws + 92274688);        // 1 KiB pad
  float* wslot  = (float*)(ws + 92275712);      // 64 KiB [2T]
  int*   perm   = (int*)(ws + 92341248);        // 256 KiB [E,T]
  bf16*  xl     = (bf16*)(ws + 92603392);       // 16 MiB [T,D] lo
  bf16*  gw1h   = (bf16*)(ws + 109380608);      //  4 MiB [H,D] hi
  bf16*  gw1l   = (bf16*)(ws + 113574912);      //  4 MiB [H,D] lo
  int*   tidx   = (int*)(ws + 113574912);       // 64 KiB [2T] (reuses gw1l: dead after gate GEMM)
  float* G1     = (float*)(ws + 117769216);     // 64 MiB [T,H] fp32
  bf16*  S1     = (bf16*)(ws + 117769216);      // 32 MiB [T,H]  (reuses G1)
  bf16*  Hrt    = (bf16*)(ws + 117769216);      // 64 MiB [2T,H] (reuses G1/S1)

  hipMemsetAsync(counts, 0, NEXP * sizeof(int), stream);

  dim3 blk(256);
  // x cast (hi+lo)
  cast_split_x<<<dim3((T_TOK * DDIM) / 1024), blk, 0, stream>>>(x, xb, xl);
  // weight cast+transpose ([K,N] fp32 -> [N,K] bf16)
  transpose_cast<true ><<<dim3(HDIM/32, DDIM/32, 1), blk, 0, stream>>>(gw1, gw1h, gw1l, DDIM, HDIM);
  transpose_cast<false><<<dim3(HDIM/32, DDIM/32, 1), blk, 0, stream>>>(Ws1, Ws1t, nullptr, DDIM, HDIM);
  transpose_cast<false><<<dim3(DDIM/32, HDIM/32, 1), blk, 0, stream>>>(Ws2, Ws2t, nullptr, HDIM, DDIM);
  transpose_cast<false><<<dim3(HDIM/32, DDIM/32, NEXP), blk, 0, stream>>>(We1, We1t, nullptr, DDIM, HDIM);
  transpose_cast<false><<<dim3(DDIM/32, HDIM/32, NEXP), blk, 0, stream>>>(We2, We2t, nullptr, HDIM, DDIM);

  // gate GEMM1 (split-bf16, fp32 out): G1 = gelu_erf(x @ gw1 + gb1)
  gemm_bt<1, float, 0, false, true><<<dim3(HDIM/128, T_TOK/128, 1), blk, 0, stream>>>(
      xb, gw1h, xl, gw1l, gb1, G1, T_TOK, HDIM, DDIM, DDIM, 0, 0,
      nullptr, nullptr, nullptr);
  // gating: logits + top-2 + softmax, then ballot-aggregated dispatch
  logits_kernel<<<dim3(T_TOK / 4), blk, 0, stream>>>(G1, gw2, gb2, tidx, wslot);
  dispatch_kernel<<<dim3(T_TOK / 256), blk, 0, stream>>>(tidx, counts, perm);
  // shared expert
  gemm_bt<2, bf16, 0, false, false><<<dim3(HDIM/128, T_TOK/128, 1), blk, 0, stream>>>(
      xb, Ws1t, nullptr, nullptr, bs1, S1, T_TOK, HDIM, DDIM, DDIM, 0, 0,
      nullptr, nullptr, nullptr);
  gemm_bt<0, float, 0, false, false><<<dim3(DDIM/128, T_TOK/128, 1), blk, 0, stream>>>(
      S1, Ws2t, nullptr, nullptr, bs2, out, T_TOK, DDIM, HDIM, HDIM, 0, 0,
      nullptr, nullptr, nullptr);
  // routed experts (gathered)
  gemm_bt<2, bf16, 1, false, false><<<dim3(HDIM/128, T_TOK/128, NEXP), blk, 0, stream>>>(
      xb, We1t, nullptr, nullptr, be1, Hrt, T_TOK, HDIM, DDIM, DDIM,
      (long)HDIM * DDIM, HDIM, perm, counts, nullptr);
  gemm_bt<0, bf16, 2, true, false><<<dim3(DDIM/128, T_TOK/128, NEXP), blk, 0, stream>>>(
      Hrt, We2t, nullptr, nullptr, be2, Rout, T_TOK, DDIM, HDIM, HDIM,
      (long)DDIM * HDIM, DDIM, perm, counts, wslot);
  // final combine (fp32)
  combine_kernel<<<dim3((T_TOK * DDIM) / 2048), blk, 0, stream>>>(Rout, out);
}

// Round 5
// 884.328 us; speedup vs baseline: 1.1777x; 1.0196x over previous
//
#include <hip/hip_runtime.h>
#include <hip/hip_bf16.h>

// DeepSeekMoE on MI355X. FP32 inputs/output per reference; bf16 MFMA compute.
// Sparse top-2 dispatch (exact vs dense reference: non-topk gates are 0).
// Gate layer-1 uses split-bf16 3-term GEMM so top-2 selection matches fp32 ref.
// R5: (1) XOR-swizzled LDS staging (kills 8-way bank conflicts in fragment
// ds_read_b128: SQ_LDS_BANK_CONFLICT was 128 cy/blk-iter = 25% of LDS time);
// (2) combine fused into shared-GEMM2 epilogue (routed GEMMs reordered first).

using bf16 = __hip_bfloat16;
typedef __attribute__((ext_vector_type(8))) short short8;
typedef __attribute__((ext_vector_type(4))) float float4v;

#define T_TOK 8192
#define DDIM  1024
#define HDIM  2048
#define NEXP  8

__device__ __forceinline__ float bf2f(short s) {
  unsigned u = ((unsigned)(unsigned short)s) << 16;
  return __builtin_bit_cast(float, u);
}
__device__ __forceinline__ unsigned short f2bf(float f) {
  unsigned u = __builtin_bit_cast(unsigned, f);
  unsigned r = (u + 0x7fffu + ((u >> 16) & 1u)) >> 16;   // RNE
  return (unsigned short)r;
}
__device__ __forceinline__ float gelu_erf_f(float x) {
  return 0.5f * x * (1.0f + erff(x * 0.70710678118654752f));
}
__device__ __forceinline__ float gelu_tanh_f(float x) {
  float t = tanhf(0.7978845608028654f * (x + 0.044715f * x * x * x));
  return 0.5f * x * (1.0f + t);
}
__device__ __forceinline__ void gld_lds16(const bf16* g, bf16* l) {
  __builtin_amdgcn_global_load_lds(
      (const __attribute__((address_space(1))) void*)g,
      (__attribute__((address_space(3))) void*)l, 16, 0, 0);
}

// ---------------- cast x fp32 -> bf16 hi + bf16 residual ----------------
__global__ __launch_bounds__(256) void cast_split_x(
    const float* __restrict__ x, bf16* __restrict__ xh, bf16* __restrict__ xl)
{
  long i = ((long)blockIdx.x * 256 + threadIdx.x) * 4;
  float4v v = *(const float4v*)(x + i);
  short4 h, l;
  short* hp = (short*)&h; short* lp = (short*)&l;
  #pragma unroll
  for (int j = 0; j < 4; ++j) {
    unsigned short hb = f2bf(v[j]);
    hp[j] = (short)hb;
    lp[j] = (short)f2bf(v[j] - bf2f((short)hb));
  }
  *(short4*)((short*)xh + i) = h;
  *(short4*)((short*)xl + i) = l;
}

// ------------- transpose+cast fp32 [R,C] -> bf16 [C,R], batched z -------------
template<bool SPLIT>
__global__ __launch_bounds__(256) void transpose_cast(
    const float* __restrict__ in, bf16* __restrict__ out,
    bf16* __restrict__ outl, int R, int C)
{
  __shared__ float tile[32][33];
  long b = blockIdx.z;
  const float* ip = in + b * (long)R * C;
  short* op = (short*)out + b * (long)R * C;
  short* opl = SPLIT ? (short*)outl + b * (long)R * C : nullptr;
  int c0 = blockIdx.x * 32, r0 = blockIdx.y * 32;
  int tx = threadIdx.x & 31, ty = threadIdx.x >> 5;
  #pragma unroll
  for (int i = ty; i < 32; i += 8)
    tile[i][tx] = ip[(long)(r0 + i) * C + c0 + tx];
  __syncthreads();
  #pragma unroll
  for (int i = ty; i < 32; i += 8) {
    float v = tile[tx][i];
    unsigned short hb = f2bf(v);
    op[(long)(c0 + i) * R + r0 + tx] = (short)hb;
    if (SPLIT)
      opl[(long)(c0 + i) * R + r0 + tx] = (short)f2bf(v - bf2f((short)hb));
  }
}

// ---------------- tiled MFMA GEMM: C = act(A @ B^T + bias) ----------------
// A [M,Kd] bf16 (ldA), Bt [N,Kd] bf16 (+z*strideB), bias fp32 [N] (+z*strideBias).
// GATHER: 0 dense; 1 A-row = perm[i]>>1 (token); 2 A-row = perm[i] (slot).
// Gathered: C row = perm[i], M_eff = counts[z], early-exit tiles.
// ACT: 0 none, 1 gelu(erf), 2 gelu(tanh). WEIGHTED: scale by wslot[slot].
// SPLIT: accumulate A@Bt + A@Btl + Al@Bt (split-bf16; dense only).
// COMBINE (dense fp32 out, N=DDIM): v += Rout[2*row] + Rout[2*row+1].
// LDS layout XOR-swizzled: chunk (row, kc16) stored at 16B-slot
// row*4 + (kc16 ^ (row&3)) -> fragment ds_read_b128 is conflict-free.
template<int ACT, typename OutT, int GATHER, bool WEIGHTED, bool SPLIT, bool COMBINE>
__global__ __launch_bounds__(256) void gemm_bt(
    const bf16* __restrict__ A, const bf16* __restrict__ Bt,
    const bf16* __restrict__ Al, const bf16* __restrict__ Btl,
    const float* __restrict__ bias, OutT* __restrict__ Cmat,
    int M, int N, int Kd, int ldA,
    long strideB, long strideBias,
    const int* __restrict__ perm, const int* __restrict__ counts,
    const float* __restrict__ wslot, const bf16* __restrict__ RoutC)
{
  __shared__ __align__(16) bf16 lA[128 * 32];
  __shared__ __align__(16) bf16 lB[128 * 32];
  __shared__ int permT[128];

  const int tid = threadIdx.x;
  const int tile_n = blockIdx.x, tile_m = blockIdx.y, z = blockIdx.z;

  int Meff = M;
  if (GATHER) {
    const int* perm_z = perm + (long)z * T_TOK;
    Meff = counts[z];
    if (tile_m * 128 >= Meff) return;   // uniform early-exit (before barriers)
    if (tid < 128) {
      int i = tile_m * 128 + tid;
      permT[tid] = perm_z[i < Meff ? i : (Meff - 1)];
    }
    __syncthreads();
  }
  const float* biasz = bias + (long)z * strideBias;

  // --- staging: 16B chunk per thread per half-tile; LDS dest MUST be
  //     lane-contiguous (global_load_lds), so the swizzle permutes which
  //     GLOBAL k-chunk each lane fetches ---
  const int i0 = tid >> 2;                            // row-in-tile (0..63)
  const int kc = (((tid & 3) ^ ((tid >> 2) & 3))) * 8; // swizzled k offset
  long rowA0, rowA1;
  if (GATHER) {
    int p0 = permT[i0], p1 = permT[i0 + 64];
    rowA0 = (GATHER == 1) ? (p0 >> 1) : p0;
    rowA1 = (GATHER == 1) ? (p1 >> 1) : p1;
  } else {
    rowA0 = (long)tile_m * 128 + i0;
    rowA1 = rowA0 + 64;
  }
  bf16* lA0 = &lA[tid * 8];
  bf16* lA1 = &lA[(tid + 256) * 8];
  bf16* lB0 = &lB[tid * 8];
  bf16* lB1 = &lB[(tid + 256) * 8];

  const int lane = tid & 63;
  const int wave = tid >> 6;
  const int wm = (wave & 1) * 64;
  const int wn = (wave >> 1) * 64;
  const int fr = lane & 15;          // m/n index within 16x16 tile
  // swizzled fragment k-offset: logical fk = (lane>>4)*8 at row with row&3=lane&3
  const int sw = (((lane >> 4) ^ (lane & 3))) * 8;

  float4v acc[4][4];
  #pragma unroll
  for (int i = 0; i < 4; ++i)
    #pragma unroll
    for (int j = 0; j < 4; ++j) acc[i][j] = {0.f, 0.f, 0.f, 0.f};

  #pragma unroll 1
  for (int ps = 0; ps < (SPLIT ? 3 : 1); ++ps) {
    const bf16* Ap = (SPLIT && ps == 2) ? Al : A;
    const bf16* Bp = (SPLIT && ps == 1) ? Btl : Bt;
    const bf16* aBase0 = Ap + rowA0 * ldA + kc;
    const bf16* aBase1 = Ap + rowA1 * ldA + kc;
    const bf16* bBase0 = Bp + (long)z * strideB
                       + ((long)tile_n * 128 + i0) * Kd + kc;
    const bf16* bBase1 = bBase0 + (long)64 * Kd;

    for (int k0 = 0; k0 < Kd; k0 += 32) {
      gld_lds16(aBase0 + k0, lA0);
      gld_lds16(aBase1 + k0, lA1);
      gld_lds16(bBase0 + k0, lB0);
      gld_lds16(bBase1 + k0, lB1);
      __syncthreads();               // drains vmcnt -> LDS tile visible

      short8 af[4], bfr[4];
      #pragma unroll
      for (int mi = 0; mi < 4; ++mi)
        af[mi] = *(const short8*)&lA[(wm + mi * 16 + fr) * 32 + sw];
      #pragma unroll
      for (int ni = 0; ni < 4; ++ni)
        bfr[ni] = *(const short8*)&lB[(wn + ni * 16 + fr) * 32 + sw];
      #pragma unroll
      for (int mi = 0; mi < 4; ++mi)
        #pragma unroll
        for (int ni = 0; ni < 4; ++ni)
          acc[mi][ni] = __builtin_amdgcn_mfma_f32_16x16x32_bf16(
              af[mi], bfr[ni], acc[mi][ni], 0, 0, 0);
      __syncthreads();               // all readers done before next staging
    }
  }

  // --- epilogue: C/D layout col(n)=lane&15, row(m)=(lane>>4)*4+reg ---
  const int rq = ((lane >> 4)) * 4;
  #pragma unroll
  for (int mi = 0; mi < 4; ++mi) {
    #pragma unroll
    for (int r = 0; r < 4; ++r) {
      int irow = wm + mi * 16 + rq + r;
      int gi = tile_m * 128 + irow;
      long crow;
      bool valid = true;
      float w = 1.f;
      if (GATHER) {
        valid = gi < Meff;
        int p = permT[irow];
        crow = p;
        if (WEIGHTED) w = valid ? wslot[p] : 0.f;
      } else {
        crow = gi;
      }
      if (valid) {
        #pragma unroll
        for (int ni = 0; ni < 4; ++ni) {
          int gcol = tile_n * 128 + wn + ni * 16 + fr;
          float v = acc[mi][ni][r] + biasz[gcol];
          if (ACT == 1) v = gelu_erf_f(v);
          else if (ACT == 2) v = gelu_tanh_f(v);
          if (WEIGHTED) v *= w;
          if (COMBINE) {
            const short* rs = (const short*)RoutC;
            v += bf2f(rs[(2 * crow) * DDIM + gcol])
               + bf2f(rs[(2 * crow + 1) * DDIM + gcol]);
          }
          long cidx = crow * (long)N + gcol;
          if (sizeof(OutT) == 4) ((float*)Cmat)[cidx] = v;
          else ((unsigned short*)Cmat)[cidx] = f2bf(v);
        }
      }
    }
  }
}

// -------- logits: one wave per token; fp32 reduce; top-2 + softmax --------
__global__ __launch_bounds__(256) void logits_kernel(
    const float* __restrict__ G1, const float* __restrict__ gw2,
    const float* __restrict__ gb2, int* __restrict__ tidx,
    float* __restrict__ wslot)
{
  int wv = threadIdx.x >> 6, lane = threadIdx.x & 63;
  int t = blockIdx.x * 4 + wv;
  const float* grow = G1 + (long)t * HDIM;
  float acc[NEXP];
  #pragma unroll
  for (int e = 0; e < NEXP; ++e) acc[e] = 0.f;
  for (int j = 0; j < HDIM / 64; ++j) {
    int h = j * 64 + lane;
    float g = grow[h];                      // coalesced across the wave
    float4v w0 = *(const float4v*)&gw2[h * NEXP];
    float4v w1 = *(const float4v*)&gw2[h * NEXP + 4];
    #pragma unroll
    for (int e = 0; e < 4; ++e) {
      acc[e]     += g * w0[e];
      acc[e + 4] += g * w1[e];
    }
  }
  #pragma unroll
  for (int off = 32; off >= 1; off >>= 1)
    #pragma unroll
    for (int e = 0; e < NEXP; ++e) acc[e] += __shfl_xor(acc[e], off);

  if (lane == 0) {
    float lg[NEXP];
    #pragma unroll
    for (int e = 0; e < NEXP; ++e) lg[e] = acc[e] + gb2[e];
    int i1 = 0;
    for (int e = 1; e < NEXP; ++e) if (lg[e] > lg[i1]) i1 = e;   // ties -> lowest
    int i2 = (i1 == 0) ? 1 : 0;
    for (int e = 0; e < NEXP; ++e) {
      if (e == i1) continue;
      if (lg[e] > lg[i2]) i2 = e;
    }
    float m = lg[i1], s = 0.f;
    #pragma unroll
    for (int e = 0; e < NEXP; ++e) s += expf(lg[e] - m);
    float inv = 1.f / s;
    tidx[2 * t]     = i1;
    tidx[2 * t + 1] = i2;
    wslot[2 * t]     = expf(lg[i1] - m) * inv;
    wslot[2 * t + 1] = expf(lg[i2] - m) * inv;
  }
}

// -------- dispatch: ballot-aggregated per-expert slot lists --------
__global__ __launch_bounds__(256) void dispatch_kernel(
    const int* __restrict__ tidx, int* __restrict__ counts,
    int* __restrict__ perm)
{
  int t = blockIdx.x * 256 + threadIdx.x;
  int lane = threadIdx.x & 63;
  #pragma unroll
  for (int k = 0; k < 2; ++k) {
    int e = tidx[2 * t + k];
    #pragma unroll
    for (int ex = 0; ex < NEXP; ++ex) {
      unsigned long long m = __ballot(e == ex);
      if (m) {                                 // wave-uniform
        int leader = __ffsll((unsigned long long)m) - 1;
        int base = 0;
        if (lane == leader) base = atomicAdd(&counts[ex], __popcll(m));
        base = __shfl(base, leader);
        if (e == ex) {
          int pos = base + __popcll(m & ((1ULL << lane) - 1ULL));
          perm[ex * T_TOK + pos] = 2 * t + k;
        }
      }
    }
  }
}

extern "C" void kernel_launch(void* const* d_in, const int* in_sizes, int n_in,
                              void* d_out, int out_size, void* d_ws, size_t ws_size,
                              hipStream_t stream)
{
  const float* x   = (const float*)d_in[0];
  // d_in[1] = task_ids (unused by reference)
  const float* gw1 = (const float*)d_in[2];
  const float* gb1 = (const float*)d_in[3];
  const float* gw2 = (const float*)d_in[4];
  const float* gb2 = (const float*)d_in[5];
  const float* We1 = (const float*)d_in[6];
  const float* be1 = (const float*)d_in[7];
  const float* We2 = (const float*)d_in[8];
  const float* be2 = (const float*)d_in[9];
  const float* Ws1 = (const float*)d_in[10];
  const float* bs1 = (const float*)d_in[11];
  const float* Ws2 = (const float*)d_in[12];
  const float* bs2 = (const float*)d_in[13];
  float* out = (float*)d_out;

  // ---- workspace layout (176.3 MiB, lifetime-overlapped) ----
  char* ws = (char*)d_ws;
  bf16*  xb     = (bf16*)(ws + 0);              // 16 MiB [T,D] hi
  bf16*  We1t   = (bf16*)(ws + 16777216);       // 32 MiB [E,H,D]
  bf16*  Rout   = (bf16*)(ws + 16777216);       // 32 MiB [2T,D] (reuses We1t)
  bf16*  We2t   = (bf16*)(ws + 50331648);       // 32 MiB [E,D,H]
  bf16*  Ws1t   = (bf16*)(ws + 83886080);       //  4 MiB [H,D]
  bf16*  Ws2t   = (bf16*)(ws + 88080384);       //  4 MiB [D,H]
  int*   counts = (int*)(ws + 92274688);        // 1 KiB pad
  float* wslot  = (float*)(ws + 92275712);      // 64 KiB [2T]
  int*   perm   = (int*)(ws + 92341248);        // 256 KiB [E,T]
  bf16*  xl     = (bf16*)(ws + 92603392);       // 16 MiB [T,D] lo
  bf16*  gw1h   = (bf16*)(ws + 109380608);      //  4 MiB [H,D] hi
  bf16*  gw1l   = (bf16*)(ws + 113574912);      //  4 MiB [H,D] lo
  int*   tidx   = (int*)(ws + 113574912);       // 64 KiB [2T] (reuses gw1l after gate GEMM)
  float* G1     = (float*)(ws + 117769216);     // 64 MiB [T,H] fp32
  bf16*  Hrt    = (bf16*)(ws + 117769216);      // 64 MiB [2T,H] (reuses G1)
  bf16*  S1     = (bf16*)(ws + 117769216);      // 32 MiB [T,H]  (reuses Hrt)

  hipMemsetAsync(counts, 0, NEXP * sizeof(int), stream);

  dim3 blk(256);
  // x cast (hi+lo)
  cast_split_x<<<dim3((T_TOK * DDIM) / 1024), blk, 0, stream>>>(x, xb, xl);
  // weight cast+transpose ([K,N] fp32 -> [N,K] bf16)
  transpose_cast<true ><<<dim3(HDIM/32, DDIM/32, 1), blk, 0, stream>>>(gw1, gw1h, gw1l, DDIM, HDIM);
  transpose_cast<false><<<dim3(HDIM/32, DDIM/32, 1), blk, 0, stream>>>(Ws1, Ws1t, nullptr, DDIM, HDIM);
  transpose_cast<false><<<dim3(DDIM/32, HDIM/32, 1), blk, 0, stream>>>(Ws2, Ws2t, nullptr, HDIM, DDIM);
  transpose_cast<false><<<dim3(HDIM/32, DDIM/32, NEXP), blk, 0, stream>>>(We1, We1t, nullptr, DDIM, HDIM);
  transpose_cast<false><<<dim3(DDIM/32, HDIM/32, NEXP), blk, 0, stream>>>(We2, We2t, nullptr, HDIM, DDIM);

  // gate GEMM1 (split-bf16, fp32 out): G1 = gelu_erf(x @ gw1 + gb1)
  gemm_bt<1, float, 0, false, true, false><<<dim3(HDIM/128, T_TOK/128, 1), blk, 0, stream>>>(
      xb, gw1h, xl, gw1l, gb1, G1, T_TOK, HDIM, DDIM, DDIM, 0, 0,
      nullptr, nullptr, nullptr, nullptr);
  // gating: logits + top-2 + softmax, then ballot-aggregated dispatch
  logits_kernel<<<dim3(T_TOK / 4), blk, 0, stream>>>(G1, gw2, gb2, tidx, wslot);
  dispatch_kernel<<<dim3(T_TOK / 256), blk, 0, stream>>>(tidx, counts, perm);
  // routed experts (gathered) -- before shared so shared GEMM2 can fuse combine
  gemm_bt<2, bf16, 1, false, false, false><<<dim3(HDIM/128, T_TOK/128, NEXP), blk, 0, stream>>>(
      xb, We1t, nullptr, nullptr, be1, Hrt, T_TOK, HDIM, DDIM, DDIM,
      (long)HDIM * DDIM, HDIM, perm, counts, nullptr, nullptr);
  gemm_bt<0, bf16, 2, true, false, false><<<dim3(DDIM/128, T_TOK/128, NEXP), blk, 0, stream>>>(
      Hrt, We2t, nullptr, nullptr, be2, Rout, T_TOK, DDIM, HDIM, HDIM,
      (long)DDIM * HDIM, DDIM, perm, counts, wslot, nullptr);
  // shared expert; GEMM2 epilogue fuses the routed combine -> final out
  gemm_bt<2, bf16, 0, false, false, false><<<dim3(HDIM/128, T_TOK/128, 1), blk, 0, stream>>>(
      xb, Ws1t, nullptr, nullptr, bs1, S1, T_TOK, HDIM, DDIM, DDIM, 0, 0,
      nullptr, nullptr, nullptr, nullptr);
  gemm_bt<0, float, 0, false, false, true><<<dim3(DDIM/128, T_TOK/128, 1), blk, 0, stream>>>(
      S1, Ws2t, nullptr, nullptr, bs2, out, T_TOK, DDIM, HDIM, HDIM, 0, 0,
      nullptr, nullptr, nullptr, Rout);
}